// Round 5
// baseline (294.128 us; speedup 1.0000x reference)
//
#include <hip/hip_runtime.h>
#include <math.h>

#define NNODES 200000
#define NG 1000
#define NPG 200
#define KNN 5
#define MD 128
#define S6 (1.0f / 6.0f)
#define HS_WORDS 26624  // 208 rows x 128 words

typedef short short8 __attribute__((ext_vector_type(8)));
typedef float floatx4 __attribute__((ext_vector_type(4)));

// ---- Hs layouts (both swizzled by sw = row&7, column-group-local) ----
// fp32 h, HALVES SPLIT (so neighbor gathers are b64 2-bank-window reads that
// the vectorizer cannot merge back to b128):
//   value (row,col): qg=col>>6, kqr=(col>>2)&15, hl=(col>>1)&1, e=col&1
//   word = row*128 + 64*qg + 32*hl + ((kqr ^ (row&7))<<1) + e
// split-bf16 x, hi/lo PLANES (A-frags read directly as short8, no unpack):
//   hi of cols [64qg+8hg .. +7] at words row*128 + (16qg + (hg^(row&7)))*4
//   lo at +32 words

// RNE bf16 split-pack (single value) — used by prepack only
__device__ __forceinline__ unsigned splitpack(float f) {
  unsigned u = __float_as_uint(f);
  unsigned hb = (u + 0x7fffu + ((u >> 16) & 1u)) >> 16;
  float hf = __uint_as_float(hb << 16);
  float r = f - hf;
  unsigned v = __float_as_uint(r);
  unsigned lb = (v + 0x7fffu + ((v >> 16) & 1u)) >> 16;
  return (hb << 16) | (lb & 0xffffu);
}

// split-pack a pair into one hi-word (2 bf16) and one lo-word (2 bf16)
__device__ __forceinline__ void sp2(float f0, float f1, unsigned* hw, unsigned* lw) {
  unsigned u0 = __float_as_uint(f0), u1 = __float_as_uint(f1);
  unsigned h0 = (u0 + 0x7fffu + ((u0 >> 16) & 1u)) >> 16;
  unsigned h1 = (u1 + 0x7fffu + ((u1 >> 16) & 1u)) >> 16;
  float r0 = f0 - __uint_as_float(h0 << 16);
  float r1 = f1 - __uint_as_float(h1 << 16);
  unsigned v0 = __float_as_uint(r0), v1 = __float_as_uint(r1);
  unsigned l0 = (v0 + 0x7fffu + ((v0 >> 16) & 1u)) >> 16;
  unsigned l1 = (v1 + 0x7fffu + ((v1 >> 16) & 1u)) >> 16;
  *hw = (h0 & 0xffffu) | (h1 << 16);
  *lw = (l0 & 0xffffu) | (l1 << 16);
}

// ---------------- kNN: one block per graph (validated) — LOCAL ids ----------------
__global__ __launch_bounds__(256) void knn_kernel(const float* __restrict__ pos,
                                                  int* __restrict__ knn) {
  __shared__ float sp[NPG * 3];
  int g = blockIdx.x;
  int t = threadIdx.x;
  for (int i = t; i < NPG * 3; i += 256) sp[i] = pos[(size_t)g * NPG * 3 + i];
  __syncthreads();
  if (t < NPG) {
    float x = sp[t * 3 + 0], y = sp[t * 3 + 1], z = sp[t * 3 + 2];
    float bd[KNN];
    int bi[KNN];
#pragma unroll
    for (int k = 0; k < KNN; k++) { bd[k] = 3.0e38f; bi[k] = 0; }
    for (int j = 0; j < NPG; j++) {
      if (j == t) continue;
      float dx = __fsub_rn(x, sp[j * 3 + 0]);
      float dy = __fsub_rn(y, sp[j * 3 + 1]);
      float dz = __fsub_rn(z, sp[j * 3 + 2]);
      float d2 = __fadd_rn(__fadd_rn(__fmul_rn(dx, dx), __fmul_rn(dy, dy)),
                           __fmul_rn(dz, dz));
      if (d2 < bd[KNN - 1]) {
        bd[KNN - 1] = d2; bi[KNN - 1] = j;
#pragma unroll
        for (int k = KNN - 1; k > 0; k--) {
          if (bd[k] < bd[k - 1]) {
            float td = bd[k]; bd[k] = bd[k - 1]; bd[k - 1] = td;
            int ti = bi[k]; bi[k] = bi[k - 1]; bi[k - 1] = ti;
          }
        }
      }
    }
#pragma unroll
    for (int k = 0; k < KNN; k++)
      knn[((size_t)g * NPG + t) * KNN + k] = bi[k];  // local id within graph
  }
}

// ---------------- embW0 = emb @ W0 (100x128 @ 128x128) ----------------
__global__ __launch_bounds__(256) void emb_gemm_kernel(const float* __restrict__ emb,
                                                       const float* __restrict__ W,
                                                       float* __restrict__ embW) {
  int idx = blockIdx.x * 256 + threadIdx.x;  // 12800 total
  int r = idx >> 7, c = idx & 127;
  float a = 0.0f;
  for (int k = 0; k < MD; k++) a += emb[r * MD + k] * W[k * MD + c];
  embW[idx] = a;
}

// ---------------- pre-pack W1,W2 into MFMA B-fragment layout (validated) ----------------
__global__ __launch_bounds__(256) void prepack_kernel(const float* __restrict__ convW,
                                                      unsigned short* __restrict__ WhiF,
                                                      unsigned short* __restrict__ WloF) {
  int idx = blockIdx.x * 256 + threadIdx.x;  // 0..4095
  int lane = idx & 63;
  int c = (idx >> 6) & 3;
  int T = (idx >> 8) & 7;
  int l = idx >> 11;  // 0..1 -> W1, W2
  const float* W = convW + (size_t)(l + 1) * MD * MD;
  int m = lane & 15, q = lane >> 4;
  int n = 16 * T + m;
  unsigned short hi[8], lo[8];
#pragma unroll
  for (int j = 0; j < 8; j++) {
    int k = 32 * c + 8 * q + j;
    unsigned p = splitpack(W[(size_t)k * MD + n]);
    hi[j] = (unsigned short)(p >> 16);
    lo[j] = (unsigned short)(p & 0xffffu);
  }
  *(short8*)(WhiF + (size_t)idx * 8) = *(short8*)hi;
  *(short8*)(WloF + (size_t)idx * 8) = *(short8*)lo;
}

// ---------------- fused per-graph megakernel ----------------
// One block = one graph, 1024 threads (16 waves), 1 block/CU (LDS-limited).
// Design for the 64-VGPR budget the allocator insists on: no register array
// lives across more than one barrier (R2-R4 lesson). R4 lesson: spill gone
// but LDS gather conflicts (21k cy/block) + unpack8 VALU dominate -> b64
// halves-split gathers + hi/lo x-planes (direct short8 A-frags).
__global__ __launch_bounds__(1024)
__attribute__((amdgpu_waves_per_eu(4, 4))) void fused_kernel(
    const int* __restrict__ z, const int* __restrict__ knn,
    const float* __restrict__ embW, const float* __restrict__ convb,
    const unsigned short* __restrict__ WhiF, const unsigned short* __restrict__ WloF,
    const float* __restrict__ rW1, const float* __restrict__ rb1,
    const float* __restrict__ rW2, const float* __restrict__ rb2,
    const float* __restrict__ rW3, const float* __restrict__ rb3,
    float* __restrict__ out) {
  __shared__ float Hs[HS_WORDS];   // 106,496 B
  __shared__ int kl[NPG * KNN];    // 4,000 B
  __shared__ float red[8 * MD];    // 4,096 B
  __shared__ float pooled[MD];
  __shared__ float h1s[64];
  __shared__ float h2s[32];

  const int g = blockIdx.x;
  const int t = threadIdx.x;

  if (t < 250) ((int4*)kl)[t] = ((const int4*)(knn + (size_t)g * NPG * KNN))[t];

  const int r = t >> 2;    // row owned in agg phases (active: r < 200)
  const int kq0 = t & 3;   // granule base
  const int swr = r & 7;

  // ---- stage h0 = embW[z] (fp32, halves-split layout) ----
  if (t < 4 * NPG) {
    const int zi = z[g * NPG + r];
    const float4* E = (const float4*)(embW + (size_t)zi * MD);
#pragma unroll
    for (int p = 0; p < 8; p++) {
      const int kq = kq0 + 4 * p;        // absolute granule 0..31
      const int qg = kq >> 4, kqr = kq & 15;
      const float4 ev = E[kq];
      float* wp = Hs + r * MD + 64 * qg + ((kqr ^ swr) << 1);
      *(float2*)wp = make_float2(ev.x, ev.y);
      *(float2*)(wp + 32) = make_float2(ev.z, ev.w);
    }
  }
  __syncthreads();

  const int lane = t & 63;
  const int wv = t >> 6;
  const int m = lane & 15;
  const int q = lane >> 4;
  const int Tc = wv & 7;   // col-tile owned by this wave
  const int hg = wv >> 3;  // row-tile group: 0 -> tiles 0..6, 1 -> tiles 7..12
  const int nrt = hg ? 6 : 7;
  const int rt0 = hg ? 7 : 0;

  // neighbor row constants (hoisted)
  int o1 = 0, o2 = 0, o3 = 0, o4 = 0, o5 = 0;
  int s1 = 0, s2 = 0, s3 = 0, s4 = 0, s5 = 0;
  if (t < 4 * NPG) {
    const int* kn = kl + r * KNN;
    // kl load above is on the same barrier path (stage h0 syncthreads)
    const int i1 = kn[0], i2 = kn[1], i3 = kn[2], i4 = kn[3], i5 = kn[4];
    o1 = i1 * MD; s1 = i1 & 7;
    o2 = i2 * MD; s2 = i2 & 7;
    o3 = i3 * MD; s3 = i3 & 7;
    o4 = i4 * MD; s4 = i4 & 7;
    o5 = i5 * MD; s5 = i5 & 7;
  }

#pragma unroll 1
  for (int l = 0; l < 2; l++) {
    const float* bb = convb + l * MD;
    // ---- agg + bias + relu + split-pack, IN PLACE, two column groups ----
#pragma unroll 1
    for (int qg = 0; qg < 2; qg++) {
      unsigned hw[4][2], lw[4][2];  // 16 regs, live across ONE barrier
      if (t < 4 * NPG) {
#pragma unroll
        for (int p4 = 0; p4 < 4; p4++) {
          const int kqr = kq0 + 4 * p4;       // within-group granule 0..15
          const int kqa = kqr + 16 * qg;      // absolute (for bias)
          const int wg = 64 * qg;
          // low halves (cols 4kqa, 4kqa+1) — b64, 2-bank windows
          const float* sp_ = Hs + r * MD + wg + ((kqr ^ swr) << 1);
          float2 s0 = *(const float2*)sp_;
          float2 a1 = *(const float2*)(Hs + o1 + wg + ((kqr ^ s1) << 1));
          s0.x += a1.x; s0.y += a1.y;
          float2 a2 = *(const float2*)(Hs + o2 + wg + ((kqr ^ s2) << 1));
          s0.x += a2.x; s0.y += a2.y;
          float2 a3 = *(const float2*)(Hs + o3 + wg + ((kqr ^ s3) << 1));
          s0.x += a3.x; s0.y += a3.y;
          float2 a4 = *(const float2*)(Hs + o4 + wg + ((kqr ^ s4) << 1));
          s0.x += a4.x; s0.y += a4.y;
          float2 a5 = *(const float2*)(Hs + o5 + wg + ((kqr ^ s5) << 1));
          s0.x += a5.x; s0.y += a5.y;
          // high halves (cols 4kqa+2, +3) at +32 words
          float2 t0 = *(const float2*)(sp_ + 32);
          float2 b1 = *(const float2*)(Hs + o1 + wg + ((kqr ^ s1) << 1) + 32);
          t0.x += b1.x; t0.y += b1.y;
          float2 b2 = *(const float2*)(Hs + o2 + wg + ((kqr ^ s2) << 1) + 32);
          t0.x += b2.x; t0.y += b2.y;
          float2 b3 = *(const float2*)(Hs + o3 + wg + ((kqr ^ s3) << 1) + 32);
          t0.x += b3.x; t0.y += b3.y;
          float2 b4 = *(const float2*)(Hs + o4 + wg + ((kqr ^ s4) << 1) + 32);
          t0.x += b4.x; t0.y += b4.y;
          float2 b5 = *(const float2*)(Hs + o5 + wg + ((kqr ^ s5) << 1) + 32);
          t0.x += b5.x; t0.y += b5.y;
          const float4 bv = ((const float4*)bb)[kqa];
          const float ox = fmaxf(s0.x * S6 + bv.x, 0.0f);
          const float oy = fmaxf(s0.y * S6 + bv.y, 0.0f);
          const float oz = fmaxf(t0.x * S6 + bv.z, 0.0f);
          const float ow = fmaxf(t0.y * S6 + bv.w, 0.0f);
          sp2(ox, oy, &hw[p4][0], &lw[p4][0]);
          sp2(oz, ow, &hw[p4][1], &lw[p4][1]);
        }
      }
      __syncthreads();  // group's fp32 reads complete
      if (t < 4 * NPG) {
        unsigned* Hu = (unsigned*)Hs;
#pragma unroll
        for (int p4 = 0; p4 < 4; p4++) {
          const int kqr = kq0 + 4 * p4;
          const int hgp = kqr >> 1;
          const int wo = (kqr & 1) * 2;
          unsigned* hp = Hu + r * MD + (16 * qg + (hgp ^ swr)) * 4 + wo;
          *(uint2*)hp = make_uint2(hw[p4][0], hw[p4][1]);
          *(uint2*)(hp + 32) = make_uint2(lw[p4][0], lw[p4][1]);
        }
      }
      __syncthreads();  // packed writes visible
    }

    // ---- MFMA: h_{l+1} = x @ W_{l+1} (split-bf16 3-product, c-outer) ----
    const unsigned short* Wh = WhiF + (size_t)l * 16384;
    const unsigned short* Wl_ = WloF + (size_t)l * 16384;
    floatx4 acc[7];
#pragma unroll
    for (int i = 0; i < 7; i++) acc[i] = (floatx4){0.f, 0.f, 0.f, 0.f};
    const int swm = m & 7;  // row&7 == m&7 (16*RT multiple of 8)
#pragma unroll
    for (int c = 0; c < 4; c++) {
      const size_t off = ((size_t)(Tc * 4 + c) * 64 + lane) * 8;
      short8 bhi = *(const short8*)(Wh + off);
      short8 blo = *(const short8*)(Wl_ + off);
      // cols 32c+8q..+7: hi granule = 16*(c>>1) + ((4*(c&1)+q)^swm)
      const int gbase = 16 * (c >> 1) + (((4 * (c & 1)) + q) ^ swm);
#pragma unroll
      for (int i = 0; i < 7; i++) {
        if (i < nrt) {
          // rows 200..207 read garbage: row-confined in MFMA, discarded
          const unsigned* base =
              (const unsigned*)Hs + (16 * (rt0 + i) + m) * MD + gbase * 4;
          short8 ahi = *(const short8*)base;         // direct, no unpack
          short8 alo = *(const short8*)(base + 32);
          acc[i] = __builtin_amdgcn_mfma_f32_16x16x32_bf16(ahi, bhi, acc[i], 0, 0, 0);
          acc[i] = __builtin_amdgcn_mfma_f32_16x16x32_bf16(ahi, blo, acc[i], 0, 0, 0);
          acc[i] = __builtin_amdgcn_mfma_f32_16x16x32_bf16(alo, bhi, acc[i], 0, 0, 0);
        }
      }
    }
    __syncthreads();  // all packed-x frag reads done before overwrite

    // ---- write-back h_{l+1} (fp32, halves-split layout) ----
    {
      const int col = 16 * Tc + m;  // C/D: col = lane&15, row = 4q + reg
      const int qgc = col >> 6;
      const int kqrc = (col >> 2) & 15;
      const int wbase = 64 * qgc + 32 * ((m >> 1) & 1) + (m & 1);
#pragma unroll
      for (int i = 0; i < 7; i++) {
        if (i < nrt) {
#pragma unroll
          for (int reg = 0; reg < 4; reg++) {
            const int row = 16 * (rt0 + i) + 4 * q + reg;
            if (row < NPG)
              Hs[row * MD + wbase + ((kqrc ^ (row & 7)) << 1)] = acc[i][reg];
          }
        }
      }
    }
    __syncthreads();
  }

  // ---- tail: x3 = relu(S6*agg(h2) + b2), in place, two column groups ----
  {
    const float* bb = convb + 2 * MD;
#pragma unroll 1
    for (int qg = 0; qg < 2; qg++) {
      float4 xv[4];  // 16 regs across ONE barrier
      if (t < 4 * NPG) {
#pragma unroll
        for (int p4 = 0; p4 < 4; p4++) {
          const int kqr = kq0 + 4 * p4;
          const int kqa = kqr + 16 * qg;
          const int wg = 64 * qg;
          const float* sp_ = Hs + r * MD + wg + ((kqr ^ swr) << 1);
          float2 s0 = *(const float2*)sp_;
          float2 a1 = *(const float2*)(Hs + o1 + wg + ((kqr ^ s1) << 1));
          s0.x += a1.x; s0.y += a1.y;
          float2 a2 = *(const float2*)(Hs + o2 + wg + ((kqr ^ s2) << 1));
          s0.x += a2.x; s0.y += a2.y;
          float2 a3 = *(const float2*)(Hs + o3 + wg + ((kqr ^ s3) << 1));
          s0.x += a3.x; s0.y += a3.y;
          float2 a4 = *(const float2*)(Hs + o4 + wg + ((kqr ^ s4) << 1));
          s0.x += a4.x; s0.y += a4.y;
          float2 a5 = *(const float2*)(Hs + o5 + wg + ((kqr ^ s5) << 1));
          s0.x += a5.x; s0.y += a5.y;
          float2 t0 = *(const float2*)(sp_ + 32);
          float2 b1 = *(const float2*)(Hs + o1 + wg + ((kqr ^ s1) << 1) + 32);
          t0.x += b1.x; t0.y += b1.y;
          float2 b2 = *(const float2*)(Hs + o2 + wg + ((kqr ^ s2) << 1) + 32);
          t0.x += b2.x; t0.y += b2.y;
          float2 b3 = *(const float2*)(Hs + o3 + wg + ((kqr ^ s3) << 1) + 32);
          t0.x += b3.x; t0.y += b3.y;
          float2 b4 = *(const float2*)(Hs + o4 + wg + ((kqr ^ s4) << 1) + 32);
          t0.x += b4.x; t0.y += b4.y;
          float2 b5 = *(const float2*)(Hs + o5 + wg + ((kqr ^ s5) << 1) + 32);
          t0.x += b5.x; t0.y += b5.y;
          const float4 bv = ((const float4*)bb)[kqa];
          xv[p4].x = fmaxf(s0.x * S6 + bv.x, 0.0f);
          xv[p4].y = fmaxf(s0.y * S6 + bv.y, 0.0f);
          xv[p4].z = fmaxf(t0.x * S6 + bv.z, 0.0f);
          xv[p4].w = fmaxf(t0.y * S6 + bv.w, 0.0f);
        }
      }
      __syncthreads();
      if (t < 4 * NPG) {
#pragma unroll
        for (int p4 = 0; p4 < 4; p4++) {
          const int kqr = kq0 + 4 * p4;
          float* wp = Hs + r * MD + 64 * qg + ((kqr ^ swr) << 1);
          *(float2*)wp = make_float2(xv[p4].x, xv[p4].y);
          *(float2*)(wp + 32) = make_float2(xv[p4].z, xv[p4].w);
        }
      }
      __syncthreads();
    }
  }

  // ---- mean pool: 8 row-groups x 128 cols (halves-split reads) ----
  {
    const int col = t & 127;
    const int j = t >> 7;  // 0..7, rows j*25..j*25+24
    const int qg = col >> 6;
    const int kqr = (col >> 2) & 15;
    const int wb = 64 * qg + 32 * ((col >> 1) & 1) + (col & 1);
    float s = 0.f;
    for (int i = 0; i < 25; i++) {
      const int row = j * 25 + i;
      s += Hs[row * MD + wb + ((kqr ^ (row & 7)) << 1)];
    }
    red[j * MD + col] = s;
  }
  __syncthreads();
  if (t < MD) {
    float p = 0.f;
#pragma unroll
    for (int j = 0; j < 8; j++) p += red[j * MD + t];
    pooled[t] = p * (1.0f / (float)NPG);
  }
  __syncthreads();

  // ---- regressor MLP ----
  if (t < 64) {
    float a = rb1[t];
    for (int c = 0; c < 128; c++) a += pooled[c] * rW1[c * 64 + t];
    h1s[t] = fmaxf(a, 0.0f);
  }
  __syncthreads();
  if (t < 32) {
    float a = rb2[t];
    for (int c = 0; c < 64; c++) a += h1s[c] * rW2[c * 32 + t];
    h2s[t] = fmaxf(a, 0.0f);
  }
  __syncthreads();
  if (t == 0) {
    float a = rb3[0];
    for (int c = 0; c < 32; c++) a += h2s[c] * rW3[c];
    out[g] = a;
  }
}

extern "C" void kernel_launch(void* const* d_in, const int* in_sizes, int n_in,
                              void* d_out, int out_size, void* d_ws, size_t ws_size,
                              hipStream_t stream) {
  const int* z = (const int*)d_in[0];
  const float* pos = (const float*)d_in[1];
  const float* emb = (const float*)d_in[3];
  const float* convW = (const float*)d_in[4];  // [3][128][128]
  const float* convb = (const float*)d_in[5];  // [3][128]
  const float* rW1 = (const float*)d_in[6];
  const float* rb1 = (const float*)d_in[7];
  const float* rW2 = (const float*)d_in[8];
  const float* rb2 = (const float*)d_in[9];
  const float* rW3 = (const float*)d_in[10];
  const float* rb3 = (const float*)d_in[11];
  float* out = (float*)d_out;

  char* ws = (char*)d_ws;
  int* knn = (int*)ws;                                      // 4,000,000 B
  float* embW = (float*)(ws + 4000000);                     // 51,200 B
  unsigned short* WhiF = (unsigned short*)(ws + 4051200);   // 65,536 B
  unsigned short* WloF = WhiF + 32768;                      // 65,536 B

  knn_kernel<<<NG, 256, 0, stream>>>(pos, knn);
  emb_gemm_kernel<<<50, 256, 0, stream>>>(emb, convW, embW);
  prepack_kernel<<<16, 256, 0, stream>>>(convW, WhiF, WloF);
  fused_kernel<<<NG, 1024, 0, stream>>>(z, knn, embW, convb, WhiF, WloF,
                                        rW1, rb1, rW2, rb2, rW3, rb3, out);
}

// Round 6
// 252.597 us; speedup vs baseline: 1.1644x; 1.1644x over previous
//
#include <hip/hip_runtime.h>
#include <math.h>

#define NNODES 200000
#define NG 1000
#define NPG 200
#define KNN 5
#define MD 128
#define S6 (1.0f / 6.0f)
#define HS_WORDS 26624  // 208 rows x 128 words, unified swizzled addressing

typedef short short8 __attribute__((ext_vector_type(8)));
typedef float floatx4 __attribute__((ext_vector_type(4)));

// RNE bf16 split-pack: returns (bf16(v) << 16) | bf16(v - bf16(v))
__device__ __forceinline__ unsigned splitpack(float f) {
  unsigned u = __float_as_uint(f);
  unsigned hb = (u + 0x7fffu + ((u >> 16) & 1u)) >> 16;
  float hf = __uint_as_float(hb << 16);
  float r = f - hf;
  unsigned v = __float_as_uint(r);
  unsigned lb = (v + 0x7fffu + ((v >> 16) & 1u)) >> 16;
  return (hb << 16) | (lb & 0xffffu);
}

__device__ __forceinline__ void unpack8(int4 u, int4 v, short8* hi, short8* lo) {
  unsigned w[8] = {(unsigned)u.x, (unsigned)u.y, (unsigned)u.z, (unsigned)u.w,
                   (unsigned)v.x, (unsigned)v.y, (unsigned)v.z, (unsigned)v.w};
  short8 h, l;
#pragma unroll
  for (int i = 0; i < 8; i++) {
    h[i] = (short)(w[i] >> 16);
    l[i] = (short)(w[i] & 0xffffu);
  }
  *hi = h;
  *lo = l;
}

// Unified swizzled addressing: value (row, col) lives at word
//   row*128 + (((col>>2) ^ (row&7)) << 2) + (col&3)
// Same mapping for fp32 h and packed split-bf16 x -> in-place column-group
// conversion. XOR keeps each granule inside its 8-granule block.
__device__ __forceinline__ float4 rd4(const float* Hs, int row, int kq) {
  return *(const float4*)(Hs + row * MD + ((kq ^ (row & 7)) << 2));
}

// ---------------- kNN: one block per graph (validated) — LOCAL ids ----------------
__global__ __launch_bounds__(256) void knn_kernel(const float* __restrict__ pos,
                                                  int* __restrict__ knn) {
  __shared__ float sp[NPG * 3];
  int g = blockIdx.x;
  int t = threadIdx.x;
  for (int i = t; i < NPG * 3; i += 256) sp[i] = pos[(size_t)g * NPG * 3 + i];
  __syncthreads();
  if (t < NPG) {
    float x = sp[t * 3 + 0], y = sp[t * 3 + 1], z = sp[t * 3 + 2];
    float bd[KNN];
    int bi[KNN];
#pragma unroll
    for (int k = 0; k < KNN; k++) { bd[k] = 3.0e38f; bi[k] = 0; }
    for (int j = 0; j < NPG; j++) {
      if (j == t) continue;
      float dx = __fsub_rn(x, sp[j * 3 + 0]);
      float dy = __fsub_rn(y, sp[j * 3 + 1]);
      float dz = __fsub_rn(z, sp[j * 3 + 2]);
      float d2 = __fadd_rn(__fadd_rn(__fmul_rn(dx, dx), __fmul_rn(dy, dy)),
                           __fmul_rn(dz, dz));
      if (d2 < bd[KNN - 1]) {
        bd[KNN - 1] = d2; bi[KNN - 1] = j;
#pragma unroll
        for (int k = KNN - 1; k > 0; k--) {
          if (bd[k] < bd[k - 1]) {
            float td = bd[k]; bd[k] = bd[k - 1]; bd[k - 1] = td;
            int ti = bi[k]; bi[k] = bi[k - 1]; bi[k - 1] = ti;
          }
        }
      }
    }
#pragma unroll
    for (int k = 0; k < KNN; k++)
      knn[((size_t)g * NPG + t) * KNN + k] = bi[k];  // local id within graph
  }
}

// ---------------- embW0 = emb @ W0 (100x128 @ 128x128) ----------------
__global__ __launch_bounds__(256) void emb_gemm_kernel(const float* __restrict__ emb,
                                                       const float* __restrict__ W,
                                                       float* __restrict__ embW) {
  int idx = blockIdx.x * 256 + threadIdx.x;  // 12800 total
  int r = idx >> 7, c = idx & 127;
  float a = 0.0f;
  for (int k = 0; k < MD; k++) a += emb[r * MD + k] * W[k * MD + c];
  embW[idx] = a;
}

// ---------------- pre-pack W1,W2 into MFMA B-fragment layout (validated) ----------------
__global__ __launch_bounds__(256) void prepack_kernel(const float* __restrict__ convW,
                                                      unsigned short* __restrict__ WhiF,
                                                      unsigned short* __restrict__ WloF) {
  int idx = blockIdx.x * 256 + threadIdx.x;  // 0..4095
  int lane = idx & 63;
  int c = (idx >> 6) & 3;
  int T = (idx >> 8) & 7;
  int l = idx >> 11;  // 0..1 -> W1, W2
  const float* W = convW + (size_t)(l + 1) * MD * MD;
  int m = lane & 15, q = lane >> 4;
  int n = 16 * T + m;
  unsigned short hi[8], lo[8];
#pragma unroll
  for (int j = 0; j < 8; j++) {
    int k = 32 * c + 8 * q + j;
    unsigned p = splitpack(W[(size_t)k * MD + n]);
    hi[j] = (unsigned short)(p >> 16);
    lo[j] = (unsigned short)(p & 0xffffu);
  }
  *(short8*)(WhiF + (size_t)idx * 8) = *(short8*)hi;
  *(short8*)(WloF + (size_t)idx * 8) = *(short8*)lo;
}

// ---------------- fused per-graph megakernel ----------------
// One block = one graph, 1024 threads (16 waves), 1 block/CU (LDS-limited).
// R5 lesson: gather conflicts are intrinsic to the 16-random-rows-per-
// instruction shape (invariant to swizzle/width; ~12 cy/inst). Fix: 8 lanes
// per row (granule slot t&7) so each row's slice covers ALL 32 banks once ->
// conflict-free for ANY neighbor rows. 200 rows = 2 register-held passes
// inside each read phase (reads-all before in-place write-all).
__global__ __launch_bounds__(1024)
__attribute__((amdgpu_waves_per_eu(4, 4))) void fused_kernel(
    const int* __restrict__ z, const int* __restrict__ knn,
    const float* __restrict__ embW, const float* __restrict__ convb,
    const unsigned short* __restrict__ WhiF, const unsigned short* __restrict__ WloF,
    const float* __restrict__ rW1, const float* __restrict__ rb1,
    const float* __restrict__ rW2, const float* __restrict__ rb2,
    const float* __restrict__ rW3, const float* __restrict__ rb3,
    float* __restrict__ out) {
  __shared__ float Hs[HS_WORDS];   // 106,496 B
  __shared__ int kl[NPG * KNN];    // 4,000 B
  __shared__ float red[8 * MD];    // 4,096 B
  __shared__ float pooled[MD];
  __shared__ float h1s[64];
  __shared__ float h2s[32];

  const int g = blockIdx.x;
  const int t = threadIdx.x;

  if (t < 250) ((int4*)kl)[t] = ((const int4*)(knn + (size_t)g * NPG * KNN))[t];

  const int rs = t >> 3;   // row slot 0..127 (8 lanes per row)
  const int g0 = t & 7;    // granule slot within 8-block

  // ---- stage h0 = embW[z] (fp32, unified addressing; 8 lanes/row) ----
  __syncthreads();  // kl visible (z reads below don't need it, but cheap)
#pragma unroll
  for (int ps = 0; ps < 2; ps++) {
    const int row = 128 * ps + rs;
    if (row < NPG) {
      const int zi = z[g * NPG + row];
      const float4* E = (const float4*)(embW + (size_t)zi * MD);
      const int sw = row & 7;
#pragma unroll
      for (int j = 0; j < 4; j++) {
        const int kq = g0 + 8 * j;
        *(float4*)(Hs + row * MD + ((kq ^ sw) << 2)) = E[kq];
      }
    }
  }
  __syncthreads();

  const int lane = t & 63;
  const int wv = t >> 6;
  const int m = lane & 15;
  const int q = lane >> 4;
  const int Tc = wv & 7;   // col-tile owned by this wave
  const int hg = wv >> 3;  // row-tile group: 0 -> tiles 0..6, 1 -> tiles 7..12
  const int nrt = hg ? 6 : 7;
  const int rt0 = hg ? 7 : 0;

#pragma unroll 1
  for (int l = 0; l < 2; l++) {
    const float* bb = convb + l * MD;
    // ---- agg + bias + relu + pack, IN PLACE, 2 column phases x 2 passes ----
#pragma unroll 1
    for (int ph = 0; ph < 2; ph++) {
      int4 pkv[2][2];  // [pass][j] — 16 regs live across ONE barrier
#pragma unroll
      for (int ps = 0; ps < 2; ps++) {
        const int row = 128 * ps + rs;
        if (row < NPG) {
          const int* kn = kl + row * KNN;
          const int i1 = kn[0], i2 = kn[1], i3 = kn[2], i4 = kn[3], i5 = kn[4];
#pragma unroll
          for (int j = 0; j < 2; j++) {
            const int kq = g0 + 8 * j + 16 * ph;
            float4 s = rd4(Hs, row, kq);
            float4 a1 = rd4(Hs, i1, kq); s.x += a1.x; s.y += a1.y; s.z += a1.z; s.w += a1.w;
            float4 a2 = rd4(Hs, i2, kq); s.x += a2.x; s.y += a2.y; s.z += a2.z; s.w += a2.w;
            float4 a3 = rd4(Hs, i3, kq); s.x += a3.x; s.y += a3.y; s.z += a3.z; s.w += a3.w;
            float4 a4 = rd4(Hs, i4, kq); s.x += a4.x; s.y += a4.y; s.z += a4.z; s.w += a4.w;
            float4 a5 = rd4(Hs, i5, kq); s.x += a5.x; s.y += a5.y; s.z += a5.z; s.w += a5.w;
            const float4 bv = ((const float4*)bb)[kq];
            pkv[ps][j].x = (int)splitpack(fmaxf(s.x * S6 + bv.x, 0.0f));
            pkv[ps][j].y = (int)splitpack(fmaxf(s.y * S6 + bv.y, 0.0f));
            pkv[ps][j].z = (int)splitpack(fmaxf(s.z * S6 + bv.z, 0.0f));
            pkv[ps][j].w = (int)splitpack(fmaxf(s.w * S6 + bv.w, 0.0f));
          }
        }
      }
      __syncthreads();  // ALL reads (both passes) done before in-place writes
      unsigned* Hu = (unsigned*)Hs;
#pragma unroll
      for (int ps = 0; ps < 2; ps++) {
        const int row = 128 * ps + rs;
        if (row < NPG) {
          const int sw = row & 7;
#pragma unroll
          for (int j = 0; j < 2; j++) {
            const int kq = g0 + 8 * j + 16 * ph;
            *(int4*)(Hu + row * MD + ((kq ^ sw) << 2)) = pkv[ps][j];
          }
        }
      }
      __syncthreads();  // packed writes visible
    }

    // ---- MFMA: h_{l+1} = x @ W_{l+1} (split-bf16 3-product, c-outer) ----
    const unsigned short* Wh = WhiF + (size_t)l * 16384;
    const unsigned short* Wl_ = WloF + (size_t)l * 16384;
    floatx4 acc[7];
#pragma unroll
    for (int i = 0; i < 7; i++) acc[i] = (floatx4){0.f, 0.f, 0.f, 0.f};
    const int swm = m & 7;  // row&7 == m&7 (16*RT multiple of 8)
#pragma unroll
    for (int c = 0; c < 4; c++) {
      const size_t off = ((size_t)(Tc * 4 + c) * 64 + lane) * 8;
      short8 bhi = *(const short8*)(Wh + off);
      short8 blo = *(const short8*)(Wl_ + off);
      const int g1 = (2 * q + 8 * c) ^ swm;
      const int g2 = (2 * q + 8 * c + 1) ^ swm;
#pragma unroll
      for (int i = 0; i < 7; i++) {
        if (i < nrt) {
          // rows 200..207 read garbage: row-confined in MFMA, discarded
          const unsigned* base = (const unsigned*)Hs + (16 * (rt0 + i) + m) * MD;
          int4 u = *(const int4*)(base + (g1 << 2));
          int4 v = *(const int4*)(base + (g2 << 2));
          short8 ahi, alo;
          unpack8(u, v, &ahi, &alo);
          acc[i] = __builtin_amdgcn_mfma_f32_16x16x32_bf16(ahi, bhi, acc[i], 0, 0, 0);
          acc[i] = __builtin_amdgcn_mfma_f32_16x16x32_bf16(ahi, blo, acc[i], 0, 0, 0);
          acc[i] = __builtin_amdgcn_mfma_f32_16x16x32_bf16(alo, bhi, acc[i], 0, 0, 0);
        }
      }
    }
    __syncthreads();  // all packed-x frag reads done before overwrite

    // ---- write-back h_{l+1} (fp32, unified addressing) ----
    {
      const int colg = 4 * Tc + (m >> 2);  // (16*Tc+m)>>2
      const int cw = m & 3;
#pragma unroll
      for (int i = 0; i < 7; i++) {
        if (i < nrt) {
#pragma unroll
          for (int reg = 0; reg < 4; reg++) {
            const int row = 16 * (rt0 + i) + 4 * q + reg;
            if (row < NPG)
              Hs[row * MD + ((colg ^ (row & 7)) << 2) + cw] = acc[i][reg];
          }
        }
      }
    }
    __syncthreads();
  }

  // ---- tail: x3 = relu(S6*agg(h2) + b2), in place, same shape ----
  {
    const float* bb = convb + 2 * MD;
#pragma unroll 1
    for (int ph = 0; ph < 2; ph++) {
      float4 xv[2][2];  // 16 regs live across ONE barrier
#pragma unroll
      for (int ps = 0; ps < 2; ps++) {
        const int row = 128 * ps + rs;
        if (row < NPG) {
          const int* kn = kl + row * KNN;
          const int i1 = kn[0], i2 = kn[1], i3 = kn[2], i4 = kn[3], i5 = kn[4];
#pragma unroll
          for (int j = 0; j < 2; j++) {
            const int kq = g0 + 8 * j + 16 * ph;
            float4 s = rd4(Hs, row, kq);
            float4 a1 = rd4(Hs, i1, kq); s.x += a1.x; s.y += a1.y; s.z += a1.z; s.w += a1.w;
            float4 a2 = rd4(Hs, i2, kq); s.x += a2.x; s.y += a2.y; s.z += a2.z; s.w += a2.w;
            float4 a3 = rd4(Hs, i3, kq); s.x += a3.x; s.y += a3.y; s.z += a3.z; s.w += a3.w;
            float4 a4 = rd4(Hs, i4, kq); s.x += a4.x; s.y += a4.y; s.z += a4.z; s.w += a4.w;
            float4 a5 = rd4(Hs, i5, kq); s.x += a5.x; s.y += a5.y; s.z += a5.z; s.w += a5.w;
            const float4 bv = ((const float4*)bb)[kq];
            xv[ps][j].x = fmaxf(s.x * S6 + bv.x, 0.0f);
            xv[ps][j].y = fmaxf(s.y * S6 + bv.y, 0.0f);
            xv[ps][j].z = fmaxf(s.z * S6 + bv.z, 0.0f);
            xv[ps][j].w = fmaxf(s.w * S6 + bv.w, 0.0f);
          }
        }
      }
      __syncthreads();
#pragma unroll
      for (int ps = 0; ps < 2; ps++) {
        const int row = 128 * ps + rs;
        if (row < NPG) {
          const int sw = row & 7;
#pragma unroll
          for (int j = 0; j < 2; j++) {
            const int kq = g0 + 8 * j + 16 * ph;
            *(float4*)(Hs + row * MD + ((kq ^ sw) << 2)) = xv[ps][j];
          }
        }
      }
      __syncthreads();
    }
  }

  // ---- mean pool: 8 row-groups x 128 cols (unified addressing reads) ----
  {
    const int col = t & 127;
    const int j = t >> 7;  // 0..7, rows j*25..j*25+24
    const int colg = col >> 2, cw = col & 3;
    float s = 0.f;
    for (int i = 0; i < 25; i++) {
      const int row = j * 25 + i;
      s += Hs[row * MD + ((colg ^ (row & 7)) << 2) + cw];
    }
    red[j * MD + col] = s;
  }
  __syncthreads();
  if (t < MD) {
    float p = 0.f;
#pragma unroll
    for (int j = 0; j < 8; j++) p += red[j * MD + t];
    pooled[t] = p * (1.0f / (float)NPG);
  }
  __syncthreads();

  // ---- regressor MLP ----
  if (t < 64) {
    float a = rb1[t];
    for (int c = 0; c < 128; c++) a += pooled[c] * rW1[c * 64 + t];
    h1s[t] = fmaxf(a, 0.0f);
  }
  __syncthreads();
  if (t < 32) {
    float a = rb2[t];
    for (int c = 0; c < 64; c++) a += h1s[c] * rW2[c * 32 + t];
    h2s[t] = fmaxf(a, 0.0f);
  }
  __syncthreads();
  if (t == 0) {
    float a = rb3[0];
    for (int c = 0; c < 32; c++) a += h2s[c] * rW3[c];
    out[g] = a;
  }
}

extern "C" void kernel_launch(void* const* d_in, const int* in_sizes, int n_in,
                              void* d_out, int out_size, void* d_ws, size_t ws_size,
                              hipStream_t stream) {
  const int* z = (const int*)d_in[0];
  const float* pos = (const float*)d_in[1];
  const float* emb = (const float*)d_in[3];
  const float* convW = (const float*)d_in[4];  // [3][128][128]
  const float* convb = (const float*)d_in[5];  // [3][128]
  const float* rW1 = (const float*)d_in[6];
  const float* rb1 = (const float*)d_in[7];
  const float* rW2 = (const float*)d_in[8];
  const float* rb2 = (const float*)d_in[9];
  const float* rW3 = (const float*)d_in[10];
  const float* rb3 = (const float*)d_in[11];
  float* out = (float*)d_out;

  char* ws = (char*)d_ws;
  int* knn = (int*)ws;                                      // 4,000,000 B
  float* embW = (float*)(ws + 4000000);                     // 51,200 B
  unsigned short* WhiF = (unsigned short*)(ws + 4051200);   // 65,536 B
  unsigned short* WloF = WhiF + 32768;                      // 65,536 B

  knn_kernel<<<NG, 256, 0, stream>>>(pos, knn);
  emb_gemm_kernel<<<50, 256, 0, stream>>>(emb, convW, embW);
  prepack_kernel<<<16, 256, 0, stream>>>(convW, WhiF, WloF);
  fused_kernel<<<NG, 1024, 0, stream>>>(z, knn, embW, convb, WhiF, WloF,
                                        rW1, rb1, rW2, rb2, rW3, rb3, out);
}